// Round 3
// baseline (490.478 us; speedup 1.0000x reference)
//
#include <hip/hip_runtime.h>

#define B_  16
#define IC  128
#define OC  256
#define ZD  256
#define HH  64
#define WW  64
#define FAN 1152      // IC*3*3
#define NO  294912    // OC*FAN
#define HP  66        // padded H/W

typedef float    fvec4 __attribute__((ext_vector_type(4)));
typedef _Float16 f16x8 __attribute__((ext_vector_type(8)));
typedef _Float16 f16x4 __attribute__((ext_vector_type(4)));

// async global->LDS, 16B/lane: lane i of the wave deposits at ldst + i*16B.
__device__ __forceinline__ void gl_lds16(const _Float16* g, _Float16* ldst) {
  __builtin_amdgcn_global_load_lds(
      (const __attribute__((address_space(1))) unsigned int*)(const void*)g,
      (__attribute__((address_space(3))) unsigned int*)(void*)ldst,
      16, 0, 0);
}

// raw barrier + counted waits: never drain vmcnt to 0 in the main loop.
#define BARRIER()  asm volatile("s_barrier" ::: "memory")
#define WAITVM8()  asm volatile("s_waitcnt vmcnt(8)" ::: "memory")
#define WAITVM4()  asm volatile("s_waitcnt vmcnt(4)" ::: "memory")
#define WAITVM0()  asm volatile("s_waitcnt vmcnt(0)" ::: "memory")
#define WAITLGKM() asm volatile("s_waitcnt lgkmcnt(0)" ::: "memory")

// ---------------------------------------------------------------------------
// FUSED Kernel A+B (unchanged, round-2 proven): one block per oc.
// ---------------------------------------------------------------------------
__global__ __launch_bounds__(512) void delta_std_fused_kernel(
    const float* __restrict__ z, const float* __restrict__ head_w,
    const float* __restrict__ base_w, _Float16* __restrict__ w_h) {
  __shared__ __align__(16) _Float16 As2[2][128 * 264];  // 135168 B stage (dbuf)
  __shared__ _Float16 zsh[16 * 264];                    // 8448 B
  __shared__ float bsh[FAN];                            // 4608 B
  __shared__ float swS[8 * 16], swQ[8 * 16];
  __shared__ float musb[16], scb[16];

  const int t = threadIdx.x;
  const int oc = blockIdx.x;
  const int lane = t & 63, wave = t >> 6;
  const int quad = lane >> 4, l16 = lane & 15;

  const float* hw = head_w + (size_t)oc * FAN * ZD;
  const float* hwp = hw + (size_t)wave * ZD + lane * 4;

  fvec4 rg[16];
#pragma unroll
  for (int i = 0; i < 16; ++i)
    rg[i] = *(const fvec4*)(hwp + (size_t)i * 8 * ZD);

  for (int u = t; u < 1024; u += 512) {
    int b = u >> 6, kq = u & 63;
    fvec4 v = *(const fvec4*)&z[b * ZD + kq * 4];
    f16x4 h = {(_Float16)v.x, (_Float16)v.y, (_Float16)v.z, (_Float16)v.w};
    *(f16x4*)&zsh[b * 264 + kq * 4] = h;
  }
  for (int u = t; u < FAN; u += 512) bsh[u] = base_w[oc * FAN + u];

  fvec4 dd[9];

#pragma unroll
  for (int c = 0; c < 9; ++c) {
    _Float16* dst = &As2[c & 1][wave * 264 + lane * 4];
#pragma unroll
    for (int i = 0; i < 16; ++i) {
      fvec4 v = rg[i];
      f16x4 h = {(_Float16)v.x, (_Float16)v.y, (_Float16)v.z, (_Float16)v.w};
      *(f16x4*)(dst + i * 8 * 264) = h;
    }
    if (c < 8) {
      const float* src = hwp + (size_t)(c + 1) * 128 * ZD;
#pragma unroll
      for (int i = 0; i < 16; ++i)
        rg[i] = *(const fvec4*)(src + (size_t)i * 8 * ZD);
    }
    WAITLGKM();
    BARRIER();
    fvec4 a = (fvec4){0.f, 0.f, 0.f, 0.f};
    const _Float16* Ab = &As2[c & 1][(wave * 16 + l16) * 264 + quad * 8];
    const _Float16* Zb = &zsh[l16 * 264 + quad * 8];
#pragma unroll
    for (int kc = 0; kc < 8; ++kc) {
      f16x8 af = *(const f16x8*)(Ab + kc * 32);
      f16x8 bz = *(const f16x8*)(Zb + kc * 32);
      a = __builtin_amdgcn_mfma_f32_16x16x32_f16(af, bz, a, 0, 0, 0);
    }
    dd[c] = a;
    WAITLGKM();
    BARRIER();
  }

  float s = 0.f, s2 = 0.f;
#pragma unroll
  for (int c = 0; c < 9; ++c)
#pragma unroll
    for (int r = 0; r < 4; ++r) { float v = dd[c][r]; s += v; s2 += v * v; }
  s  += __shfl_xor(s, 16);  s  += __shfl_xor(s, 32);
  s2 += __shfl_xor(s2, 16); s2 += __shfl_xor(s2, 32);
  if (lane < 16) { swS[wave * 16 + l16] = s; swQ[wave * 16 + l16] = s2; }
  __syncthreads();
  if (t < 16) {
    float S = 0.f, S2 = 0.f;
#pragma unroll
    for (int w = 0; w < 8; ++w) { S += swS[w * 16 + t]; S2 += swQ[w * 16 + t]; }
    const float inv_fan = 1.0f / (float)FAN;
    float mu  = S * inv_fan;
    float var = S2 * inv_fan - mu * mu;
    const float inv_sqrt2 = 0.70710678118654752f;
    musb[t] = mu;
    scb[t]  = rsqrtf(var + 1e-5f) * sqrtf(2.0f / (float)FAN) * inv_sqrt2;
  }
  __syncthreads();

  float* dsh = (float*)&As2[0][0];
#pragma unroll
  for (int c = 0; c < 9; ++c) {
    int jb = c * 128 + wave * 16 + quad * 4;
#pragma unroll
    for (int r = 0; r < 4; ++r)
      dsh[(jb + r) * 17 + l16] = dd[c][r];
  }
  __syncthreads();

  const float inv_sqrt2 = 0.70710678118654752f;
  for (int u = t; u < 2304; u += 512) {
    int b = u / 144, seg = u % 144;
    int p0 = seg * 8;
    int kk = p0 >> 7, ic0 = p0 & 127;
    float mu = musb[b], sc = scb[b];
    _Float16 h[8];
#pragma unroll
    for (int e = 0; e < 8; ++e) {
      int j = (ic0 + e) * 9 + kk;
      float val = bsh[j] * inv_sqrt2 + (dsh[j * 17 + b] - mu) * sc;
      h[e] = (_Float16)val;
    }
    *(f16x8*)&w_h[((size_t)b * OC + oc) * FAN + p0] = *(f16x8*)h;
  }
}

// ---------------------------------------------------------------------------
// Kernel X: x (f32 NCHW) -> x_h (f16 NHWC, zero-padded [16][66][66][128]).
// (unchanged)
// ---------------------------------------------------------------------------
__global__ __launch_bounds__(256) void xpose_kernel(
    const float* __restrict__ x, _Float16* __restrict__ x_h) {
  int yp = blockIdx.x;
  int b  = blockIdx.y;
  int t  = threadIdx.x;
  _Float16* orow = x_h + ((size_t)(b * HP + yp)) * HP * IC;

  if (yp == 0 || yp == HP - 1) {
    fvec4 zz = (fvec4){0.f, 0.f, 0.f, 0.f};
    for (int u = t; u < HP * IC / 8; u += 256)
      ((fvec4*)orow)[u] = zz;
    return;
  }
  int y = yp - 1;
  __shared__ float tile[128 * 65];
#pragma unroll
  for (int i = 0; i < 8; ++i) {
    int F = i * 256 + t;
    int ic = F >> 4, xq = F & 15;
    fvec4 v = *(const fvec4*)&x[(((size_t)b * IC + ic) * HH + y) * WW + xq * 4];
    float* tp = &tile[ic * 65 + xq * 4];
    tp[0] = v.x; tp[1] = v.y; tp[2] = v.z; tp[3] = v.w;
  }
  __syncthreads();
#pragma unroll
  for (int j = 0; j < 4; ++j) {
    int u = j * 256 + t;
    int px = u >> 4, icg = u & 15;
    _Float16 h[8];
#pragma unroll
    for (int c = 0; c < 8; ++c) h[c] = (_Float16)tile[(icg * 8 + c) * 65 + px];
    *(f16x8*)&orow[(px + 1) * IC + icg * 8] = *(f16x8*)h;
  }
  if (t < 32) {
    int side = t >> 4, icg = t & 15;
    fvec4 zz = (fvec4){0.f, 0.f, 0.f, 0.f};
    *(fvec4*)&orow[(side ? (HP - 1) * IC : 0) + icg * 8] = zz;
  }
}

// ---------------------------------------------------------------------------
// Kernel C (8-PHASE REWRITE): implicit-GEMM conv, f16 MFMA 16x16x32.
// 256 oc x 256 px tile, K = 1152 = 18 K-tiles of 64, split into 4-slot
// K-COLUMN ring per operand: slot(kt,ks) = (kt*2+ks)&3, each [256 r][32 k]
// = 16 KB. K-col split => slot (kt,0) dies after phase 1 of kt, enabling
// in-ring staging with uniform counted vmcnt(8) (gap stage->use >= 5 phases
// at 2 gl_lds/phase; tail peels use vmcnt(4)/vmcnt(0)).
// Phase = (ks, nf-half): {ds_read frags | 1 stage unit | vmcnt(8) | barrier |
// 16 MFMA (setprio) | barrier}. A-frags register-cached across the h pair.
// Swizzle: seg' = seg ^ (row&3) ^ ((row>>2)&3) -> every frag read is a dense
// 1 KB permutation (2 lanes/bank = free); gl_lds dest lane-linear with
// pre-swizzled per-lane source (both-sides-or-neither rule).
// Grid: (16 px-tiles of 4 image rows, 16 b) = 256 blocks, 512 thr (2M x 4N).
// K order (tap, icc, ks) identical to prior version => bit-identical accum.
// ---------------------------------------------------------------------------
__global__ __launch_bounds__(512, 2) void conv_mfma_kernel(
    const _Float16* __restrict__ x_h, const _Float16* __restrict__ w_h,
    float* __restrict__ out) {
  __shared__ __align__(16) _Float16 As[4 * 8192];   // 64 KB ring
  __shared__ __align__(16) _Float16 Bs[4 * 8192];   // 64 KB ring
  const int t = threadIdx.x;
  const int b = blockIdx.y;
  const int y0 = blockIdx.x * 4;
  const int lane = t & 63, wave = t >> 6;
  const int wm = wave >> 2, wn = wave & 3;
  const int quad = lane >> 4, l16 = lane & 15;

  fvec4 acc[8][4];
#pragma unroll
  for (int i = 0; i < 8; ++i)
#pragma unroll
    for (int j = 0; j < 4; ++j) acc[i][j] = (fvec4){0.f, 0.f, 0.f, 0.f};

  // stage mapping: per gl_lds instr lane -> row lr = lane>>2, dest seg lane&3
  const int lr = lane >> 2;
  const int sw = (lane & 3) ^ (lr & 3) ^ ((lr >> 2) & 3);   // source seg

  // A stage sources: rows oc = wave*32 + i*16 + lr (whole M=256 per K-unit)
  const _Float16* apg0 = w_h + ((size_t)(b * OC + wave * 32 + lr)) * FAN + sw * 8;
  const _Float16* apg1 = apg0 + (size_t)16 * FAN;
  // B stage sources: px p = wave*32 + i*16 + lr; y = y0+(p>>6)[+ky], x=(p&63)[+kx]
  const int p0 = wave * 32 + lr, p1 = p0 + 16;
  const _Float16* bpg0 =
      x_h + (((size_t)(b * HP + y0 + (p0 >> 6))) * HP + (p0 & 63)) * IC + sw * 8;
  const _Float16* bpg1 =
      x_h + (((size_t)(b * HP + y0 + (p1 >> 6))) * HP + (p1 & 63)) * IC + sw * 8;

  const int dst0 = wave * 1024;            // dest halves: (wave*32 rows)*32

  // fragment read offsets (halves): row stride 32, seg = quad ^ f(row)
  const int xoro = (l16 & 3) ^ ((l16 >> 2) & 3);
  const int kseg = (quad ^ xoro) << 3;
  const int arow = (wm * 128 + l16) * 32 + kseg;   // + mf*512
  const int brow = (wn * 64 + l16) * 32 + kseg;    // + (h*2+nf)*512

#define STAGE_A(KT, KS) do {                                        \
    int sl_ = (((KT) * 2 + (KS)) & 3);                              \
    int co_ = (KT) * 64 + (KS) * 32;                                \
    gl_lds16(apg0 + co_, As + sl_ * 8192 + dst0);                   \
    gl_lds16(apg1 + co_, As + sl_ * 8192 + dst0 + 512);             \
  } while (0)
#define STAGE_B(KT, KS) do {                                        \
    int sl_ = (((KT) * 2 + (KS)) & 3);                              \
    int tap_ = (KT) >> 1;                                           \
    int ky_ = (tap_ * 11) >> 5;                                     \
    int kx_ = tap_ - ky_ * 3;                                       \
    int co_ = (ky_ * HP + kx_) * IC + ((KT) & 1) * 64 + (KS) * 32;  \
    gl_lds16(bpg0 + co_, Bs + sl_ * 8192 + dst0);                   \
    gl_lds16(bpg1 + co_, Bs + sl_ * 8192 + dst0 + 512);             \
  } while (0)
#define MFMA16(H)                                                   \
    __builtin_amdgcn_s_setprio(1);                                  \
    _Pragma("unroll")                                               \
    for (int mf = 0; mf < 8; ++mf) {                                \
      acc[mf][(H)*2]   = __builtin_amdgcn_mfma_f32_16x16x32_f16(af[mf], bf0, acc[mf][(H)*2],   0, 0, 0); \
      acc[mf][(H)*2+1] = __builtin_amdgcn_mfma_f32_16x16x32_f16(af[mf], bf1, acc[mf][(H)*2+1], 0, 0, 0); \
    }                                                               \
    __builtin_amdgcn_s_setprio(0);

#define KT_BODY(KT, S01, S23, VM1, VM3) {                           \
    const int sA0 = (((KT) * 2) & 3) * 8192;                        \
    const int sA1 = (((KT) * 2 + 1) & 3) * 8192;                    \
    f16x8 af[8], bf0, bf1;                                          \
    /* phase 0: ks=0, nf 0,1 */                                     \
    _Pragma("unroll")                                               \
    for (int mf = 0; mf < 8; ++mf)                                  \
      af[mf] = *(const f16x8*)&As[sA0 + arow + mf * 512];           \
    bf0 = *(const f16x8*)&Bs[sA0 + brow];                           \
    bf1 = *(const f16x8*)&Bs[sA0 + brow + 512];                     \
    if (S01) STAGE_A((KT) + 1, 1);                                  \
    WAITVM8(); BARRIER();                                           \
    MFMA16(0);                                                      \
    BARRIER();                                                      \
    /* phase 1: ks=0, nf 2,3 */                                     \
    bf0 = *(const f16x8*)&Bs[sA0 + brow + 1024];                    \
    bf1 = *(const f16x8*)&Bs[sA0 + brow + 1536];                    \
    if (S01) STAGE_B((KT) + 1, 1);                                  \
    VM1; BARRIER();                                                 \
    MFMA16(1);                                                      \
    BARRIER();                                                      \
    /* phase 2: ks=1, nf 0,1 */                                     \
    _Pragma("unroll")                                               \
    for (int mf = 0; mf < 8; ++mf)                                  \
      af[mf] = *(const f16x8*)&As[sA1 + arow + mf * 512];           \
    bf0 = *(const f16x8*)&Bs[sA1 + brow];                           \
    bf1 = *(const f16x8*)&Bs[sA1 + brow + 512];                     \
    if (S23) STAGE_A((KT) + 2, 0);                                  \
    WAITVM8(); BARRIER();                                           \
    MFMA16(0);                                                      \
    BARRIER();                                                      \
    /* phase 3: ks=1, nf 2,3 */                                     \
    bf0 = *(const f16x8*)&Bs[sA1 + brow + 1024];                    \
    bf1 = *(const f16x8*)&Bs[sA1 + brow + 1536];                    \
    if (S23) STAGE_B((KT) + 2, 0);                                  \
    VM3; BARRIER();                                                 \
    MFMA16(1);                                                      \
    BARRIER();                                                      \
  }

  // prologue: (0,0),(0,1),(1,0) staged; vmcnt(8) lands (0,0) (12 issued)
  STAGE_A(0, 0); STAGE_B(0, 0);
  STAGE_A(0, 1); STAGE_B(0, 1);
  STAGE_A(1, 0); STAGE_B(1, 0);
  WAITVM8(); BARRIER();

#pragma unroll 1
  for (int kt = 0; kt < 16; ++kt)
    KT_BODY(kt, 1, 1, WAITVM8(), WAITVM8());
  // kt=16: stage only (17,1); p3 wait vmcnt(4) forces (17,0) landed
  KT_BODY(16, 1, 0, WAITVM8(), WAITVM4());
  // kt=17: no stages; p1 wait vmcnt(0) forces (17,1) landed
  KT_BODY(17, 0, 0, WAITVM0(), (void)0);

#undef KT_BODY
#undef MFMA16
#undef STAGE_B
#undef STAGE_A

  // epilogue (validated): D row = oc (quad*4 + r), col = px (l16)
#pragma unroll
  for (int mf = 0; mf < 8; ++mf)
#pragma unroll
    for (int nf = 0; nf < 4; ++nf) {
      int oc = wm * 128 + mf * 16 + quad * 4;
      int pn = wn * 64 + nf * 16 + l16;
      int oy = y0 + (pn >> 6), ox = pn & 63;
      float* op = out + (((size_t)(b * OC + oc) * HH + oy) * WW + ox);
#pragma unroll
      for (int r = 0; r < 4; ++r)
        op[(size_t)r * HH * WW] = acc[mf][nf][r];
    }
}

// ---------------------------------------------------------------------------
extern "C" void kernel_launch(void* const* d_in, const int* in_sizes, int n_in,
                              void* d_out, int out_size, void* d_ws, size_t ws_size,
                              hipStream_t stream) {
  const float* x      = (const float*)d_in[0];  // [16,128,64,64]
  const float* z      = (const float*)d_in[1];  // [16,256]
  const float* base_w = (const float*)d_in[2];  // [256,128,3,3]
  const float* head_w = (const float*)d_in[3];  // [294912,256]
  float* out = (float*)d_out;                   // [16,256,64,64]

  // ws layout (~27 MB of ~1.2 GB):
  //   [0)        w_h  f16  9.44 MB
  //   [+9.44MB)  x_h  f16 17.84 MB
  _Float16* w_h = (_Float16*)d_ws;
  _Float16* x_h = (_Float16*)((char*)d_ws + (size_t)B_ * OC * FAN * sizeof(_Float16));

  delta_std_fused_kernel<<<OC, 512, 0, stream>>>(z, head_w, base_w, w_h);
  xpose_kernel<<<dim3(HP, B_), 256, 0, stream>>>(x, x_h);
  conv_mfma_kernel<<<dim3(16, B_), 512, 0, stream>>>(x_h, w_h, out);
}